// Round 12
// baseline (165.673 us; speedup 1.0000x reference)
//
#include <hip/hip_runtime.h>

// GCN link-prediction forward: 2× GCNConv (128->128 relu, 128->64) on
// N=50000 nodes, E=800000 random edges. fp32 compute, int8 messages.
//
// Algebra: with dis[n] = rsqrt(indeg[n]+1),
//   conv(x)[c] = ( sum_{r->c} h[r]*dis[r] + h[c]*dis[c] ) * dis[c] + b,
//   h = x@W (unscaled). Messages stored int8 per-row quantized (biased +128;
//   exact -128 correction via K = sum of scales).
//
// R2: scatter-atomics -> CSR gather (2737 -> 920 us).
// R3: register-tiled GEMM + shfl scan (920 -> 369 us).
// R4: hierarchical scan, float4 GEMM frags, gather unroll (369 -> 312 us).
// R5: bf16 message storage halves random-gather traffic (312 -> 276 us).
// R6: CSR build -> two-level bucketed counting sort (276 -> 223 us).
// R7: VALU GEMM -> MFMA 16x16x32 bf16 (223 -> 196 us).
// R8: fixed bucket windows; GEMM2 fused into gather1 (196 -> 179 us).
// R9: gemm1 fused with edge-partition; per-edge dis; ushort csr (179 -> 169).
// R10: src-sorted gather: +1% -- locality hypothesis falsified.
// R11: layer-1 messages int8 (128B rows = 2 lines) (169 -> 161 us).
// R12: layer-2 messages int8 too (h2 rows 128B -> 64B = 1 line): halves
//      gather2's random line count; gather2 restructured 4 lanes/node,
//      bitonic sort dropped (neutral per R10).

typedef unsigned int u32;
typedef unsigned short ushort;
typedef __attribute__((ext_vector_type(8))) short short8;
typedef __attribute__((ext_vector_type(4))) float floatx4;

static inline int cdiv_l(long a, int b) { return (int)((a + b - 1) / b); }

constexpr int NPB  = 512;    // nodes per bucket (2^9)
constexpr int EPB  = 4096;   // edges per partition block
constexpr int MAXB = 128;    // max buckets (N <= 65536)
constexpr int CAP  = 12288;  // per-bucket edge capacity (mean 8163, +5sigma 8616)

__device__ __forceinline__ u32 pack_bf16(float a, float b) {
  union { float f; u32 i; } ua, ub;
  ua.f = a; ub.f = b;
  u32 x = (ua.i + 0x7fffu + ((ua.i >> 16) & 1u)) >> 16;           // rne, low
  u32 y = (ub.i + 0x7fffu + ((ub.i >> 16) & 1u)) & 0xffff0000u;   // rne, high
  return x | y;
}

__device__ __forceinline__ short bf16r(float f) {
  union { float f; u32 i; } u; u.f = f;
  return (short)((u.i + 0x7fffu + ((u.i >> 16) & 1u)) >> 16);     // rne
}

// int8 dequant-accumulate: 8 biased uint8 -> acc += (float)q * sd
__device__ __forceinline__ void dq8(float* a, uint2 v, float sd) {
  a[0] += (float)(v.x & 255u) * sd;
  a[1] += (float)((v.x >> 8) & 255u) * sd;
  a[2] += (float)((v.x >> 16) & 255u) * sd;
  a[3] += (float)(v.x >> 24) * sd;
  a[4] += (float)(v.y & 255u) * sd;
  a[5] += (float)((v.y >> 8) & 255u) * sd;
  a[6] += (float)((v.y >> 16) & 255u) * sd;
  a[7] += (float)(v.y >> 24) * sd;
}

// 16-wide variant for 64B layer-2 rows.
__device__ __forceinline__ void dq16(float* a, uint4 v, float s) {
  a[0]  += (float)(v.x & 255u) * s;
  a[1]  += (float)((v.x >> 8) & 255u) * s;
  a[2]  += (float)((v.x >> 16) & 255u) * s;
  a[3]  += (float)(v.x >> 24) * s;
  a[4]  += (float)(v.y & 255u) * s;
  a[5]  += (float)((v.y >> 8) & 255u) * s;
  a[6]  += (float)((v.y >> 16) & 255u) * s;
  a[7]  += (float)(v.y >> 24) * s;
  a[8]  += (float)(v.z & 255u) * s;
  a[9]  += (float)((v.z >> 8) & 255u) * s;
  a[10] += (float)((v.z >> 16) & 255u) * s;
  a[11] += (float)(v.z >> 24) * s;
  a[12] += (float)(v.w & 255u) * s;
  a[13] += (float)((v.w >> 8) & 255u) * s;
  a[14] += (float)((v.w >> 16) & 255u) * s;
  a[15] += (float)(v.w >> 24) * s;
}

// Bitonic ascending sort of one value per lane across W-lane partitions.
template <int W>
__device__ __forceinline__ int lane_sort(int v, int l) {
#pragma unroll
  for (int k = 2; k <= W; k <<= 1) {
#pragma unroll
    for (int j = k >> 1; j > 0; j >>= 1) {
      int o = __shfl_xor(v, j, W);
      bool asc = ((l & k) == 0);
      bool low = ((l & j) == 0);
      v = (asc == low) ? min(v, o) : max(v, o);
    }
  }
  return v;
}

// ---- fused dispatch 1: blocks [0,NBE) partition edges into bucket windows;
// ---- blocks [NBE,..) compute h8 = int8(x@W1) + per-row scale (no dis).
__global__ __launch_bounds__(256) void k_fused1(
    const int* __restrict__ ei, int* __restrict__ cur, u32* __restrict__ ebuf,
    int E, int NBE,
    const float* __restrict__ x, const float* __restrict__ W1,
    u32* __restrict__ h8, float* __restrict__ scale, int N) {
  __shared__ float eb[4][16 * 133];   // gemm epilogue staging (34 KB)
  const int tid = threadIdx.x;

  if (blockIdx.x < (unsigned)NBE) {
    // ===== edge partition (counting sort pass 1), LDS edge cache =====
    u32* ecache = (u32*)&eb[0][0];          // 4096 u32 = 16 KB (in eb[0..1])
    int* hist   = (int*)&eb[2][0];          // MAXB ints (in eb[2])
    int* curs   = hist + MAXB;
    const int* ecol = ei + E;
    if (tid < MAXB) hist[tid] = 0;
    __syncthreads();
    const int base = blockIdx.x * EPB;
#pragma unroll
    for (int j = 0; j < EPB / 256; ++j) {
      int e = base + j * 256 + tid;
      u32 pk = 0xffffffffu;
      if (e < E) {
        u32 r = (u32)ei[e];
        u32 c = (u32)ecol[e];
        pk = r | (c << 16);
        atomicAdd(hist + (c >> 9), 1);
      }
      ecache[j * 256 + tid] = pk;
    }
    __syncthreads();
    if (tid < MAXB) {
      int n = hist[tid];
      curs[tid] = tid * CAP + (n ? atomicAdd(cur + tid, n) : 0);
    }
    __syncthreads();
#pragma unroll
    for (int j = 0; j < EPB / 256; ++j) {
      u32 pk = ecache[j * 256 + tid];
      if (pk != 0xffffffffu) {
        u32 c = pk >> 16;
        int b = c >> 9;
        int p = atomicAdd(curs + b, 1);
        if (p < (b + 1) * CAP)  // overflow guard (statistically impossible)
          ebuf[p] = (pk & 0xffffu) | ((c & (NPB - 1)) << 16);
      }
    }
    return;
  }

  // ===== MFMA GEMM1: h8[row,:] = int8(x[row,:] @ W1), K=M=128 =====
  constexpr int K = 128, M = 128, NC = 8, LROW = 133;
  const int w = tid >> 6, lane = tid & 63;
  const int quad = lane >> 4, n16 = lane & 15;
  const int row0 = ((blockIdx.x - NBE) * 4 + w) * 16;

  floatx4 acc[NC];
#pragma unroll
  for (int c = 0; c < NC; ++c) acc[c] = {0.f, 0.f, 0.f, 0.f};

  const int am = row0 + n16;
  const bool av = am < N;
  const float* arow = x + (long)am * K;

#pragma unroll
  for (int kc = 0; kc < 4; ++kc) {
    const int kb = kc * 32 + quad * 8;
    float4 a0 = make_float4(0.f, 0.f, 0.f, 0.f);
    float4 a1 = make_float4(0.f, 0.f, 0.f, 0.f);
    if (av) {
      a0 = *(const float4*)(arow + kb);
      a1 = *(const float4*)(arow + kb + 4);
    }
    short8 af;
    af[0] = bf16r(a0.x); af[1] = bf16r(a0.y); af[2] = bf16r(a0.z); af[3] = bf16r(a0.w);
    af[4] = bf16r(a1.x); af[5] = bf16r(a1.y); af[6] = bf16r(a1.z); af[7] = bf16r(a1.w);
    const float* wbase = W1 + (long)kb * M + n16;
#pragma unroll
    for (int c = 0; c < NC; ++c) {
      const float* wp = wbase + c * 16;
      short8 bf;
      bf[0] = bf16r(wp[0 * M]); bf[1] = bf16r(wp[1 * M]);
      bf[2] = bf16r(wp[2 * M]); bf[3] = bf16r(wp[3 * M]);
      bf[4] = bf16r(wp[4 * M]); bf[5] = bf16r(wp[5 * M]);
      bf[6] = bf16r(wp[6 * M]); bf[7] = bf16r(wp[7 * M]);
      acc[c] = __builtin_amdgcn_mfma_f32_16x16x32_bf16(af, bf, acc[c], 0, 0, 0);
    }
  }

  float* ep = eb[w];
#pragma unroll
  for (int c = 0; c < NC; ++c)
#pragma unroll
    for (int r = 0; r < 4; ++r)
      ep[(quad * 4 + r) * LROW + c * 16 + n16] = acc[c][r];
  __syncthreads();

  // int8 quantize: lane -> row rr = lane>>2, col segment seg*32..+31
  const int rr = lane >> 2, seg = lane & 3;
  const float* rowp = ep + rr * LROW + seg * 32;
  float m = 0.f;
#pragma unroll
  for (int c = 0; c < 32; ++c) m = fmaxf(m, fabsf(rowp[c]));
  m = fmaxf(m, __shfl_xor(m, 1, 4));
  m = fmaxf(m, __shfl_xor(m, 2, 4));
  const float inv = (m > 0.f) ? 127.f / m : 0.f;
  const float s = m / 127.f;
  u32 q[8];
#pragma unroll
  for (int wd = 0; wd < 8; ++wd) {
    u32 b0 = (u32)((int)rintf(rowp[wd * 4 + 0] * inv) + 128);
    u32 b1 = (u32)((int)rintf(rowp[wd * 4 + 1] * inv) + 128);
    u32 b2 = (u32)((int)rintf(rowp[wd * 4 + 2] * inv) + 128);
    u32 b3 = (u32)((int)rintf(rowp[wd * 4 + 3] * inv) + 128);
    q[wd] = (b0 & 255u) | ((b1 & 255u) << 8) | ((b2 & 255u) << 16) | (b3 << 24);
  }
  const int rg = row0 + rr;
  if (rg < N) {
    uint4* dst = (uint4*)(h8 + (long)rg * 32 + seg * 8);
    dst[0] = make_uint4(q[0], q[1], q[2], q[3]);
    dst[1] = make_uint4(q[4], q[5], q[6], q[7]);
    if (seg == 0) scale[rg] = s;
  }
}

// ---- dispatch 2: per-bucket CSR finalize + sd = scale*dis fold ----
__global__ __launch_bounds__(NPB) void k_csr(const u32* __restrict__ ebuf,
                                             const int* __restrict__ cur,
                                             const float* __restrict__ scale,
                                             int* __restrict__ off,
                                             int* __restrict__ deg,
                                             float* __restrict__ dis,
                                             float* __restrict__ sd,
                                             ushort* __restrict__ csr, int N) {
  __shared__ int cnt[NPB];
  __shared__ int curl[NPB];
  __shared__ int wsum[NPB / 64];
  const int tid = threadIdx.x;
  const int b = blockIdx.x;
  const int s = b * CAP;
  const int e = s + min(cur[b], CAP);
  cnt[tid] = 0;
  __syncthreads();
  for (int i = s + tid; i < e; i += NPB)
    atomicAdd(cnt + (ebuf[i] >> 16), 1);
  __syncthreads();
  const int lane = tid & 63, w = tid >> 6;
  int v = cnt[tid];
  int incl = v;
#pragma unroll
  for (int d = 1; d < 64; d <<= 1) {
    int x = __shfl_up(incl, d, 64);
    if (lane >= d) incl += x;
  }
  if (lane == 63) wsum[w] = incl;
  __syncthreads();
  if (w == 0 && lane < NPB / 64) {
    int sv = wsum[lane];
#pragma unroll
    for (int d = 1; d < NPB / 64; d <<= 1) {
      int x = __shfl_up(sv, d, 64);
      if (lane >= d) sv += x;
    }
    wsum[lane] = sv;
  }
  __syncthreads();
  int excl = ((w > 0) ? wsum[w - 1] : 0) + incl - v;
  int node = b * NPB + tid;
  if (node < N) {
    float dv = rsqrtf((float)v + 1.0f);
    off[node] = s + excl;
    deg[node] = v;
    dis[node] = dv;
    sd[node] = scale[node] * dv;
  }
  curl[tid] = excl;
  __syncthreads();
  for (int i = s + tid; i < e; i += NPB) {
    u32 pk = ebuf[i];
    int p = atomicAdd(curl + (pk >> 16), 1);
    csr[s + p] = (ushort)(pk & 0xffffu);
  }
}

// ---- dispatch 3: fused gather1 (int8 msgs) + relu + GEMM2 + int8-requant ----
__global__ __launch_bounds__(256) void k_gg(
    const uint2* __restrict__ h8, const int* __restrict__ off,
    const int* __restrict__ deg, const ushort* __restrict__ csr,
    const float* __restrict__ dis, const float* __restrict__ sd,
    const float* __restrict__ b1, const float* __restrict__ W2,
    u32* __restrict__ h82, float* __restrict__ scale2, int N) {
  constexpr int LG = 65;   // u32 words per g row (64 + pad)
  constexpr int LC = 66;   // f32 words per C row (64 + pad)
  __shared__ u32 lg[16 * LG];
  __shared__ float cb[16 * LC];
  const int tid = threadIdx.x;
  const int r = tid >> 4;          // local node 0..15
  const int lf = tid & 15;         // lane within 16-group (8-byte chunk)
  const int row0 = blockIdx.x * 16;
  const int n = row0 + r;

  // ---- phase 1: int8 gather (rows = 128B = 2 lines) ----
  u32 gw[4] = {0, 0, 0, 0};
  if (n < N) {
    const int s = off[n], e = s + deg[n];
    const float dn = dis[n];
    float acc[8] = {};
    float K = 0.f;
    {
      float sn = sd[n];
      dq8(acc, h8[(long)n * 16 + lf], sn);  // self-loop
      K += sn;
    }
    for (int j = s; j < e; j += 16) {
      int idx = j + lf;
      int cs = (idx < e) ? (int)csr[idx] : 0x7fffffff;
      cs = lane_sort<16>(cs, lf);
      const int cnt = min(e - j, 16);
      int t = 0;
      for (; t + 4 <= cnt; t += 4) {
        int s0 = __shfl(cs, t, 16);
        int s1 = __shfl(cs, t + 1, 16);
        int s2 = __shfl(cs, t + 2, 16);
        int s3 = __shfl(cs, t + 3, 16);
        float d0 = sd[s0], d1 = sd[s1], d2 = sd[s2], d3 = sd[s3];
        uint2 v0 = h8[(long)s0 * 16 + lf];
        uint2 v1 = h8[(long)s1 * 16 + lf];
        uint2 v2 = h8[(long)s2 * 16 + lf];
        uint2 v3 = h8[(long)s3 * 16 + lf];
        dq8(acc, v0, d0); dq8(acc, v1, d1); dq8(acc, v2, d2); dq8(acc, v3, d3);
        K += (d0 + d1) + (d2 + d3);
      }
      for (; t < cnt; ++t) {
        int s0 = __shfl(cs, t, 16);
        float d0 = sd[s0];
        dq8(acc, h8[(long)s0 * 16 + lf], d0);
        K += d0;
      }
    }
    const int f8 = lf * 8;
    const float4 bv0 = *(const float4*)(b1 + f8);
    const float4 bv1 = *(const float4*)(b1 + f8 + 4);
    const float bb[8] = {bv0.x, bv0.y, bv0.z, bv0.w, bv1.x, bv1.y, bv1.z, bv1.w};
    const float kc = 128.f * K;
#pragma unroll
    for (int q = 0; q < 8; ++q)
      acc[q] = fmaxf((acc[q] - kc) * dn + bb[q], 0.f);
#pragma unroll
    for (int q = 0; q < 4; ++q)
      gw[q] = pack_bf16(acc[2 * q], acc[2 * q + 1]);
  }
#pragma unroll
  for (int q = 0; q < 4; ++q) lg[r * LG + lf * 4 + q] = gw[q];
  __syncthreads();

  // ---- phase 2: 16x128x64 MFMA; wave w owns cols w*16..w*16+15 ----
  const int w = tid >> 6, lane = tid & 63;
  const int quad = lane >> 4, n16 = lane & 15;
  floatx4 acc4 = {0.f, 0.f, 0.f, 0.f};
#pragma unroll
  for (int kc = 0; kc < 4; ++kc) {
    const int kb = kc * 32 + quad * 8;
    const u32* ap = &lg[n16 * LG + (kb >> 1)];
    u32 aw[4] = {ap[0], ap[1], ap[2], ap[3]};
    short8 af = *(short8*)aw;
    const float* wp = W2 + (long)kb * 64 + w * 16 + n16;
    short8 bf;
    bf[0] = bf16r(wp[0 * 64]); bf[1] = bf16r(wp[1 * 64]);
    bf[2] = bf16r(wp[2 * 64]); bf[3] = bf16r(wp[3 * 64]);
    bf[4] = bf16r(wp[4 * 64]); bf[5] = bf16r(wp[5 * 64]);
    bf[6] = bf16r(wp[6 * 64]); bf[7] = bf16r(wp[7 * 64]);
    acc4 = __builtin_amdgcn_mfma_f32_16x16x32_bf16(af, bf, acc4, 0, 0, 0);
  }
  float dd[4];
#pragma unroll
  for (int r4 = 0; r4 < 4; ++r4) {
    int rg = row0 + quad * 4 + r4;
    dd[r4] = (rg < N) ? dis[rg] : 0.f;
  }
#pragma unroll
  for (int r4 = 0; r4 < 4; ++r4)
    cb[(quad * 4 + r4) * LC + w * 16 + n16] = acc4[r4] * dd[r4];
  __syncthreads();

  // ---- int8 requantize h2: row rr, 4 cols per 16-lane; width-16 shfl max ----
  {
    const int rr = tid >> 4, lf2 = tid & 15;
    const float* rowp = cb + rr * LC + lf2 * 4;
    float m = fmaxf(fmaxf(fabsf(rowp[0]), fabsf(rowp[1])),
                    fmaxf(fabsf(rowp[2]), fabsf(rowp[3])));
    m = fmaxf(m, __shfl_xor(m, 1, 16));
    m = fmaxf(m, __shfl_xor(m, 2, 16));
    m = fmaxf(m, __shfl_xor(m, 4, 16));
    m = fmaxf(m, __shfl_xor(m, 8, 16));
    const float inv = (m > 0.f) ? 127.f / m : 0.f;
    u32 b0 = (u32)((int)rintf(rowp[0] * inv) + 128);
    u32 b1v = (u32)((int)rintf(rowp[1] * inv) + 128);
    u32 b2 = (u32)((int)rintf(rowp[2] * inv) + 128);
    u32 b3 = (u32)((int)rintf(rowp[3] * inv) + 128);
    u32 p = (b0 & 255u) | ((b1v & 255u) << 8) | ((b2 & 255u) << 16) | (b3 << 24);
    const int rg = row0 + rr;
    if (rg < N) {
      h82[(long)rg * 16 + lf2] = p;
      if (lf2 == 0) scale2[rg] = m / 127.f;
    }
  }
}

// ---- dispatch 4: layer-2 gather (int8 h82, 64B rows, 4 lanes/node) ----
__global__ __launch_bounds__(256) void k_gather2(
    const uint4* __restrict__ h82, const int* __restrict__ off,
    const int* __restrict__ deg, const ushort* __restrict__ csr,
    const float* __restrict__ dis, const float* __restrict__ scale2,
    const float* __restrict__ bias, float* __restrict__ out, int N) {
  const int local = threadIdx.x >> 2;   // 64 nodes per block
  const int lf = threadIdx.x & 3;       // 16 feats per lane
  const int n = blockIdx.x * 64 + local;
  if (n >= N) return;
  const int s = off[n], e = s + deg[n];
  float acc[16] = {};
  float K = 0.f;
  {
    float s2 = scale2[n];
    dq16(acc, h82[(long)n * 4 + lf], s2);  // self-loop
    K += s2;
  }
  for (int j = s; j < e; j += 4) {
    int idx = j + lf;
    int cs = (idx < e) ? (int)csr[idx] : 0;
    const int cnt = min(e - j, 4);
#pragma unroll
    for (int t = 0; t < 4; ++t) {
      if (t < cnt) {
        int s0 = __shfl(cs, t, 4);
        float s2 = scale2[s0];
        dq16(acc, h82[(long)s0 * 4 + lf], s2);
        K += s2;
      }
    }
  }
  const float d = dis[n];
  const float kc = 128.f * K;
  const int f16 = lf * 16;
#pragma unroll
  for (int q4 = 0; q4 < 4; ++q4) {
    float4 bv = *(const float4*)(bias + f16 + q4 * 4);
    float4 o;
    o.x = (acc[q4 * 4 + 0] - kc) * d + bv.x;
    o.y = (acc[q4 * 4 + 1] - kc) * d + bv.y;
    o.z = (acc[q4 * 4 + 2] - kc) * d + bv.z;
    o.w = (acc[q4 * 4 + 3] - kc) * d + bv.w;
    *(float4*)(out + (long)n * 64 + f16 + q4 * 4) = o;
  }
}

extern "C" void kernel_launch(void* const* d_in, const int* in_sizes, int n_in,
                              void* d_out, int out_size, void* d_ws, size_t ws_size,
                              hipStream_t stream) {
  const float* x  = (const float*)d_in[0];
  const int*   ei = (const int*)d_in[1];   // [2,E] int32
  const float* W1 = (const float*)d_in[4];
  const float* b1 = (const float*)d_in[5];
  const float* W2 = (const float*)d_in[6];
  const float* b2 = (const float*)d_in[7];
  float* out = (float*)d_out;

  const int N = in_sizes[0] / 128;
  const int E = in_sizes[1] / 2;
  const int NBKT = cdiv_l(N, NPB);   // 98 (<=128; N<=65536 for 16-bit pack)
  const int NBE  = cdiv_l(E, EPB);   // 196
  const int G1   = cdiv_l(N, 64);    // 782 gemm1 blocks

  // workspace layout (4-byte elems):
  //   cur[128] | off[Np] | deg[Np] | dis[Np] | scale[Np] | sd[Np] | scale2[Np]
  //   | ebuf[BW u32] | csr[BW ushort] | h8[N*32 u32] | h82[N*16 u32]
  const long Np = (N + 64) & ~63L;
  const long BW = (long)NBKT * CAP;
  int*    cur    = (int*)d_ws;
  int*    off    = cur + 128;
  int*    deg    = off + Np;
  float*  dis    = (float*)(deg + Np);
  float*  scale  = dis + Np;
  float*  sd     = scale + Np;
  float*  scale2 = sd + Np;
  u32*    ebuf   = (u32*)(scale2 + Np);
  ushort* csr    = (ushort*)(ebuf + BW);
  u32*    h8     = (u32*)(csr + BW);     // BW ushorts = BW/2 u32 words
  u32*    h82    = h8 + (long)N * 32;

  // ---- cursors -> 0 (windows are fixed; offsets are relative) ----
  hipMemsetAsync(cur, 0, MAXB * sizeof(int), stream);

  // ---- fused: edge partition (blocks 0..NBE) || GEMM1+int8 (blocks NBE..) ----
  k_fused1<<<NBE + G1, 256, 0, stream>>>(ei, cur, ebuf, E, NBE, x, W1, h8,
                                         scale, N);

  // ---- per-bucket CSR finalize (+ sd fold) ----
  k_csr<<<NBKT, NPB, 0, stream>>>(ebuf, cur, scale, off, deg, dis, sd, csr, N);

  // ---- gather1 (int8) + relu + GEMM2 + int8 requant fused ----
  k_gg<<<cdiv_l(N, 16), 256, 0, stream>>>((const uint2*)h8, off, deg, csr,
                                          dis, sd, b1, W2, h82, scale2, N);

  // ---- layer-2 gather (int8) + bias ----
  k_gather2<<<cdiv_l(N, 64), 256, 0, stream>>>((const uint4*)h82, off, deg, csr,
                                               dis, scale2, b2, out, N);
}

// Round 13
// 158.111 us; speedup vs baseline: 1.0478x; 1.0478x over previous
//
#include <hip/hip_runtime.h>

// GCN link-prediction forward: 2× GCNConv (128->128 relu, 128->64) on
// N=50000 nodes, E=800000 random edges. fp32 compute, int8/bf16 messages.
//
// Algebra: with dis[n] = rsqrt(indeg[n]+1),
//   conv(x)[c] = ( sum_{r->c} h[r]*dis[r] + h[c]*dis[c] ) * dis[c] + b,
//   h = x@W (unscaled). Layer-1 messages stored int8 (per-row scale,
//   biased +128; exact -128 correction via K = sum of scales).
//
// R2: scatter-atomics -> CSR gather (2737 -> 920 us).
// R3: register-tiled GEMM + shfl scan (920 -> 369 us).
// R4: hierarchical scan, float4 GEMM frags, gather unroll (369 -> 312 us).
// R5: bf16 message storage halves random-gather traffic (312 -> 276 us).
// R6: CSR build -> two-level bucketed counting sort (276 -> 223 us).
// R7: VALU GEMM -> MFMA 16x16x32 bf16 (223 -> 196 us).
// R8: fixed bucket windows; GEMM2 fused into gather1 (196 -> 179 us).
// R9: gemm1 fused with edge-partition; per-edge dis; ushort csr (179 -> 169).
// R10: src-sorted gather: +1% -- locality hypothesis falsified.
// R11: layer-1 messages int8 (128B rows = 2 lines) (169 -> 161 us).
// R12: layer-2 int8 REGRESSED (165.7 us) -- gather2 is latency-bound, not
//      traffic-bound; restructure cut per-node parallelism. REVERTED.
// R13: exact R11 configuration (best known: 161.5 us).

typedef unsigned int u32;
typedef unsigned short ushort;
typedef __attribute__((ext_vector_type(8))) short short8;
typedef __attribute__((ext_vector_type(4))) float floatx4;

static inline int cdiv_l(long a, int b) { return (int)((a + b - 1) / b); }

constexpr int NPB  = 512;    // nodes per bucket (2^9)
constexpr int EPB  = 4096;   // edges per partition block
constexpr int MAXB = 128;    // max buckets (N <= 65536)
constexpr int CAP  = 12288;  // per-bucket edge capacity (mean 8163, +5sigma 8616)

__device__ __forceinline__ u32 pack_bf16(float a, float b) {
  union { float f; u32 i; } ua, ub;
  ua.f = a; ub.f = b;
  u32 x = (ua.i + 0x7fffu + ((ua.i >> 16) & 1u)) >> 16;           // rne, low
  u32 y = (ub.i + 0x7fffu + ((ub.i >> 16) & 1u)) & 0xffff0000u;   // rne, high
  return x | y;
}

__device__ __forceinline__ short bf16r(float f) {
  union { float f; u32 i; } u; u.f = f;
  return (short)((u.i + 0x7fffu + ((u.i >> 16) & 1u)) >> 16);     // rne
}

__device__ __forceinline__ void add8(float* a, uint4 v) {
  union { u32 i; float f; } t;
  t.i = v.x << 16;         a[0] += t.f;
  t.i = v.x & 0xffff0000u; a[1] += t.f;
  t.i = v.y << 16;         a[2] += t.f;
  t.i = v.y & 0xffff0000u; a[3] += t.f;
  t.i = v.z << 16;         a[4] += t.f;
  t.i = v.z & 0xffff0000u; a[5] += t.f;
  t.i = v.w << 16;         a[6] += t.f;
  t.i = v.w & 0xffff0000u; a[7] += t.f;
}

// int8 dequant-accumulate: 8 biased uint8 -> acc += (float)q * sd
// (the -128 bias is corrected once per node via K = sum of sd).
__device__ __forceinline__ void dq8(float* a, uint2 v, float sd) {
  a[0] += (float)(v.x & 255u) * sd;
  a[1] += (float)((v.x >> 8) & 255u) * sd;
  a[2] += (float)((v.x >> 16) & 255u) * sd;
  a[3] += (float)(v.x >> 24) * sd;
  a[4] += (float)(v.y & 255u) * sd;
  a[5] += (float)((v.y >> 8) & 255u) * sd;
  a[6] += (float)((v.y >> 16) & 255u) * sd;
  a[7] += (float)(v.y >> 24) * sd;
}

// Bitonic ascending sort of one value per lane across W-lane partitions.
template <int W>
__device__ __forceinline__ int lane_sort(int v, int l) {
#pragma unroll
  for (int k = 2; k <= W; k <<= 1) {
#pragma unroll
    for (int j = k >> 1; j > 0; j >>= 1) {
      int o = __shfl_xor(v, j, W);
      bool asc = ((l & k) == 0);
      bool low = ((l & j) == 0);
      v = (asc == low) ? min(v, o) : max(v, o);
    }
  }
  return v;
}

// ---- fused dispatch 1: blocks [0,NBE) partition edges into bucket windows;
// ---- blocks [NBE,..) compute h8 = int8(x@W1) + per-row scale (no dis).
__global__ __launch_bounds__(256) void k_fused1(
    const int* __restrict__ ei, int* __restrict__ cur, u32* __restrict__ ebuf,
    int E, int NBE,
    const float* __restrict__ x, const float* __restrict__ W1,
    u32* __restrict__ h8, float* __restrict__ scale, int N) {
  __shared__ float eb[4][16 * 133];   // gemm epilogue staging (34 KB)
  const int tid = threadIdx.x;

  if (blockIdx.x < (unsigned)NBE) {
    // ===== edge partition (counting sort pass 1), LDS edge cache =====
    u32* ecache = (u32*)&eb[0][0];          // 4096 u32 = 16 KB (in eb[0..1])
    int* hist   = (int*)&eb[2][0];          // MAXB ints (in eb[2])
    int* curs   = hist + MAXB;
    const int* ecol = ei + E;
    if (tid < MAXB) hist[tid] = 0;
    __syncthreads();
    const int base = blockIdx.x * EPB;
#pragma unroll
    for (int j = 0; j < EPB / 256; ++j) {
      int e = base + j * 256 + tid;
      u32 pk = 0xffffffffu;
      if (e < E) {
        u32 r = (u32)ei[e];
        u32 c = (u32)ecol[e];
        pk = r | (c << 16);
        atomicAdd(hist + (c >> 9), 1);
      }
      ecache[j * 256 + tid] = pk;
    }
    __syncthreads();
    if (tid < MAXB) {
      int n = hist[tid];
      curs[tid] = tid * CAP + (n ? atomicAdd(cur + tid, n) : 0);
    }
    __syncthreads();
#pragma unroll
    for (int j = 0; j < EPB / 256; ++j) {
      u32 pk = ecache[j * 256 + tid];
      if (pk != 0xffffffffu) {
        u32 c = pk >> 16;
        int b = c >> 9;
        int p = atomicAdd(curs + b, 1);
        if (p < (b + 1) * CAP)  // overflow guard (statistically impossible)
          ebuf[p] = (pk & 0xffffu) | ((c & (NPB - 1)) << 16);
      }
    }
    return;
  }

  // ===== MFMA GEMM1: h8[row,:] = int8(x[row,:] @ W1), K=M=128 =====
  constexpr int K = 128, M = 128, NC = 8, LROW = 133;
  const int w = tid >> 6, lane = tid & 63;
  const int quad = lane >> 4, n16 = lane & 15;
  const int row0 = ((blockIdx.x - NBE) * 4 + w) * 16;

  floatx4 acc[NC];
#pragma unroll
  for (int c = 0; c < NC; ++c) acc[c] = {0.f, 0.f, 0.f, 0.f};

  const int am = row0 + n16;
  const bool av = am < N;
  const float* arow = x + (long)am * K;

#pragma unroll
  for (int kc = 0; kc < 4; ++kc) {
    const int kb = kc * 32 + quad * 8;
    float4 a0 = make_float4(0.f, 0.f, 0.f, 0.f);
    float4 a1 = make_float4(0.f, 0.f, 0.f, 0.f);
    if (av) {
      a0 = *(const float4*)(arow + kb);
      a1 = *(const float4*)(arow + kb + 4);
    }
    short8 af;
    af[0] = bf16r(a0.x); af[1] = bf16r(a0.y); af[2] = bf16r(a0.z); af[3] = bf16r(a0.w);
    af[4] = bf16r(a1.x); af[5] = bf16r(a1.y); af[6] = bf16r(a1.z); af[7] = bf16r(a1.w);
    const float* wbase = W1 + (long)kb * M + n16;
#pragma unroll
    for (int c = 0; c < NC; ++c) {
      const float* wp = wbase + c * 16;
      short8 bf;
      bf[0] = bf16r(wp[0 * M]); bf[1] = bf16r(wp[1 * M]);
      bf[2] = bf16r(wp[2 * M]); bf[3] = bf16r(wp[3 * M]);
      bf[4] = bf16r(wp[4 * M]); bf[5] = bf16r(wp[5 * M]);
      bf[6] = bf16r(wp[6 * M]); bf[7] = bf16r(wp[7 * M]);
      acc[c] = __builtin_amdgcn_mfma_f32_16x16x32_bf16(af, bf, acc[c], 0, 0, 0);
    }
  }

  float* ep = eb[w];
#pragma unroll
  for (int c = 0; c < NC; ++c)
#pragma unroll
    for (int r = 0; r < 4; ++r)
      ep[(quad * 4 + r) * LROW + c * 16 + n16] = acc[c][r];
  __syncthreads();

  // int8 quantize: lane -> row rr = lane>>2, col segment seg*32..+31
  const int rr = lane >> 2, seg = lane & 3;
  const float* rowp = ep + rr * LROW + seg * 32;
  float m = 0.f;
#pragma unroll
  for (int c = 0; c < 32; ++c) m = fmaxf(m, fabsf(rowp[c]));
  m = fmaxf(m, __shfl_xor(m, 1, 4));
  m = fmaxf(m, __shfl_xor(m, 2, 4));
  const float inv = (m > 0.f) ? 127.f / m : 0.f;
  const float s = m / 127.f;
  u32 q[8];
#pragma unroll
  for (int wd = 0; wd < 8; ++wd) {
    u32 b0 = (u32)((int)rintf(rowp[wd * 4 + 0] * inv) + 128);
    u32 b1 = (u32)((int)rintf(rowp[wd * 4 + 1] * inv) + 128);
    u32 b2 = (u32)((int)rintf(rowp[wd * 4 + 2] * inv) + 128);
    u32 b3 = (u32)((int)rintf(rowp[wd * 4 + 3] * inv) + 128);
    q[wd] = (b0 & 255u) | ((b1 & 255u) << 8) | ((b2 & 255u) << 16) | (b3 << 24);
  }
  const int rg = row0 + rr;
  if (rg < N) {
    uint4* dst = (uint4*)(h8 + (long)rg * 32 + seg * 8);
    dst[0] = make_uint4(q[0], q[1], q[2], q[3]);
    dst[1] = make_uint4(q[4], q[5], q[6], q[7]);
    if (seg == 0) scale[rg] = s;
  }
}

// ---- dispatch 2: per-bucket CSR finalize + sd = scale*dis fold ----
__global__ __launch_bounds__(NPB) void k_csr(const u32* __restrict__ ebuf,
                                             const int* __restrict__ cur,
                                             const float* __restrict__ scale,
                                             int* __restrict__ off,
                                             int* __restrict__ deg,
                                             float* __restrict__ dis,
                                             float* __restrict__ sd,
                                             ushort* __restrict__ csr, int N) {
  __shared__ int cnt[NPB];
  __shared__ int curl[NPB];
  __shared__ int wsum[NPB / 64];
  const int tid = threadIdx.x;
  const int b = blockIdx.x;
  const int s = b * CAP;
  const int e = s + min(cur[b], CAP);
  cnt[tid] = 0;
  __syncthreads();
  for (int i = s + tid; i < e; i += NPB)
    atomicAdd(cnt + (ebuf[i] >> 16), 1);
  __syncthreads();
  const int lane = tid & 63, w = tid >> 6;
  int v = cnt[tid];
  int incl = v;
#pragma unroll
  for (int d = 1; d < 64; d <<= 1) {
    int x = __shfl_up(incl, d, 64);
    if (lane >= d) incl += x;
  }
  if (lane == 63) wsum[w] = incl;
  __syncthreads();
  if (w == 0 && lane < NPB / 64) {
    int sv = wsum[lane];
#pragma unroll
    for (int d = 1; d < NPB / 64; d <<= 1) {
      int x = __shfl_up(sv, d, 64);
      if (lane >= d) sv += x;
    }
    wsum[lane] = sv;
  }
  __syncthreads();
  int excl = ((w > 0) ? wsum[w - 1] : 0) + incl - v;
  int node = b * NPB + tid;
  if (node < N) {
    float dv = rsqrtf((float)v + 1.0f);
    off[node] = s + excl;
    deg[node] = v;
    dis[node] = dv;
    sd[node] = scale[node] * dv;
  }
  curl[tid] = excl;
  __syncthreads();
  for (int i = s + tid; i < e; i += NPB) {
    u32 pk = ebuf[i];
    int p = atomicAdd(curl + (pk >> 16), 1);
    csr[s + p] = (ushort)(pk & 0xffffu);
  }
}

// ---- dispatch 3: fused gather1 (int8 msgs, src-sorted) + relu + GEMM2 ----
__global__ __launch_bounds__(256) void k_gg(
    const uint2* __restrict__ h8, const int* __restrict__ off,
    const int* __restrict__ deg, const ushort* __restrict__ csr,
    const float* __restrict__ dis, const float* __restrict__ sd,
    const float* __restrict__ b1, const float* __restrict__ W2,
    u32* __restrict__ h2, int N) {
  constexpr int LG = 65;   // u32 words per g row (64 + pad)
  constexpr int LC = 66;   // f32 words per C row (64 + pad)
  __shared__ u32 lg[16 * LG];
  __shared__ float cb[16 * LC];
  const int tid = threadIdx.x;
  const int r = tid >> 4;          // local node 0..15
  const int lf = tid & 15;         // lane within 16-group (8-byte chunk)
  const int row0 = blockIdx.x * 16;
  const int n = row0 + r;

  // ---- phase 1: int8 gather (rows = 128B = 2 lines) ----
  u32 gw[4] = {0, 0, 0, 0};
  if (n < N) {
    const int s = off[n], e = s + deg[n];
    const float dn = dis[n];
    float acc[8] = {};
    float K = 0.f;
    {
      float sn = sd[n];
      dq8(acc, h8[(long)n * 16 + lf], sn);  // self-loop
      K += sn;
    }
    for (int j = s; j < e; j += 16) {
      int idx = j + lf;
      int cs = (idx < e) ? (int)csr[idx] : 0x7fffffff;
      cs = lane_sort<16>(cs, lf);
      const int cnt = min(e - j, 16);
      int t = 0;
      for (; t + 4 <= cnt; t += 4) {
        int s0 = __shfl(cs, t, 16);
        int s1 = __shfl(cs, t + 1, 16);
        int s2 = __shfl(cs, t + 2, 16);
        int s3 = __shfl(cs, t + 3, 16);
        float d0 = sd[s0], d1 = sd[s1], d2 = sd[s2], d3 = sd[s3];
        uint2 v0 = h8[(long)s0 * 16 + lf];
        uint2 v1 = h8[(long)s1 * 16 + lf];
        uint2 v2 = h8[(long)s2 * 16 + lf];
        uint2 v3 = h8[(long)s3 * 16 + lf];
        dq8(acc, v0, d0); dq8(acc, v1, d1); dq8(acc, v2, d2); dq8(acc, v3, d3);
        K += (d0 + d1) + (d2 + d3);
      }
      for (; t < cnt; ++t) {
        int s0 = __shfl(cs, t, 16);
        float d0 = sd[s0];
        dq8(acc, h8[(long)s0 * 16 + lf], d0);
        K += d0;
      }
    }
    const int f8 = lf * 8;
    const float4 bv0 = *(const float4*)(b1 + f8);
    const float4 bv1 = *(const float4*)(b1 + f8 + 4);
    const float bb[8] = {bv0.x, bv0.y, bv0.z, bv0.w, bv1.x, bv1.y, bv1.z, bv1.w};
    const float kc = 128.f * K;
#pragma unroll
    for (int q = 0; q < 8; ++q)
      acc[q] = fmaxf((acc[q] - kc) * dn + bb[q], 0.f);
#pragma unroll
    for (int q = 0; q < 4; ++q)
      gw[q] = pack_bf16(acc[2 * q], acc[2 * q + 1]);
  }
#pragma unroll
  for (int q = 0; q < 4; ++q) lg[r * LG + lf * 4 + q] = gw[q];
  __syncthreads();

  // ---- phase 2: 16x128x64 MFMA; wave w owns cols w*16..w*16+15 ----
  const int w = tid >> 6, lane = tid & 63;
  const int quad = lane >> 4, n16 = lane & 15;
  floatx4 acc4 = {0.f, 0.f, 0.f, 0.f};
#pragma unroll
  for (int kc = 0; kc < 4; ++kc) {
    const int kb = kc * 32 + quad * 8;
    const u32* ap = &lg[n16 * LG + (kb >> 1)];
    u32 aw[4] = {ap[0], ap[1], ap[2], ap[3]};
    short8 af = *(short8*)aw;
    const float* wp = W2 + (long)kb * 64 + w * 16 + n16;
    short8 bf;
    bf[0] = bf16r(wp[0 * 64]); bf[1] = bf16r(wp[1 * 64]);
    bf[2] = bf16r(wp[2 * 64]); bf[3] = bf16r(wp[3 * 64]);
    bf[4] = bf16r(wp[4 * 64]); bf[5] = bf16r(wp[5 * 64]);
    bf[6] = bf16r(wp[6 * 64]); bf[7] = bf16r(wp[7 * 64]);
    acc4 = __builtin_amdgcn_mfma_f32_16x16x32_bf16(af, bf, acc4, 0, 0, 0);
  }
  float dd[4];
#pragma unroll
  for (int r4 = 0; r4 < 4; ++r4) {
    int rg = row0 + quad * 4 + r4;
    dd[r4] = (rg < N) ? dis[rg] : 0.f;
  }
#pragma unroll
  for (int r4 = 0; r4 < 4; ++r4)
    cb[(quad * 4 + r4) * LC + w * 16 + n16] = acc4[r4] * dd[r4];
  __syncthreads();

#pragma unroll
  for (int i = 0; i < 2; ++i) {
    int idx = i * 256 + tid;
    int rr = idx >> 5, cw = idx & 31;
    int rg = row0 + rr;
    if (rg < N) {
      u32 p = pack_bf16(cb[rr * LC + 2 * cw], cb[rr * LC + 2 * cw + 1]);
      h2[(long)rg * 32 + cw] = p;
    }
  }
}

// ---- dispatch 4: layer-2 gather (bf16 h2, pre-scaled, src-sorted) + bias ----
__global__ __launch_bounds__(256) void k_gather2(
    const uint4* __restrict__ hs, const int* __restrict__ off,
    const int* __restrict__ deg, const ushort* __restrict__ csr,
    const float* __restrict__ dis, const float* __restrict__ bias,
    float* __restrict__ out, int N) {
  constexpr int L = 8;  // lanes per node
  const int local = threadIdx.x / L;
  const int lf = threadIdx.x % L;
  const int n = blockIdx.x * (256 / L) + local;
  if (n >= N) return;
  const int s = off[n], e = s + deg[n];
  float acc[8] = {};
  add8(acc, hs[(long)n * L + lf]);  // self-loop
  for (int j = s; j < e; j += 8) {
    int idx = j + lf;
    int cs = (idx < e) ? (int)csr[idx] : 0x7fffffff;
    cs = lane_sort<8>(cs, lf);
    const int cnt = min(e - j, 8);
    int t = 0;
    for (; t + 4 <= cnt; t += 4) {
      int s0 = __shfl(cs, t, 8);
      int s1 = __shfl(cs, t + 1, 8);
      int s2 = __shfl(cs, t + 2, 8);
      int s3 = __shfl(cs, t + 3, 8);
      uint4 v0 = hs[(long)s0 * L + lf];
      uint4 v1 = hs[(long)s1 * L + lf];
      uint4 v2 = hs[(long)s2 * L + lf];
      uint4 v3 = hs[(long)s3 * L + lf];
      add8(acc, v0); add8(acc, v1); add8(acc, v2); add8(acc, v3);
    }
    for (; t < cnt; ++t) {
      int s0 = __shfl(cs, t, 8);
      add8(acc, hs[(long)s0 * L + lf]);
    }
  }
  const float d = dis[n];
  const int f8 = lf * 8;
  const float4 b0 = *(const float4*)(bias + f8);
  const float4 b1v = *(const float4*)(bias + f8 + 4);
  float4 o0, o1;
  o0.x = acc[0] * d + b0.x;
  o0.y = acc[1] * d + b0.y;
  o0.z = acc[2] * d + b0.z;
  o0.w = acc[3] * d + b0.w;
  o1.x = acc[4] * d + b1v.x;
  o1.y = acc[5] * d + b1v.y;
  o1.z = acc[6] * d + b1v.z;
  o1.w = acc[7] * d + b1v.w;
  *(float4*)(out + (long)n * 64 + f8) = o0;
  *(float4*)(out + (long)n * 64 + f8 + 4) = o1;
}

extern "C" void kernel_launch(void* const* d_in, const int* in_sizes, int n_in,
                              void* d_out, int out_size, void* d_ws, size_t ws_size,
                              hipStream_t stream) {
  const float* x  = (const float*)d_in[0];
  const int*   ei = (const int*)d_in[1];   // [2,E] int32
  const float* W1 = (const float*)d_in[4];
  const float* b1 = (const float*)d_in[5];
  const float* W2 = (const float*)d_in[6];
  const float* b2 = (const float*)d_in[7];
  float* out = (float*)d_out;

  const int N = in_sizes[0] / 128;
  const int E = in_sizes[1] / 2;
  const int NBKT = cdiv_l(N, NPB);   // 98 (<=128; N<=65536 for 16-bit pack)
  const int NBE  = cdiv_l(E, EPB);   // 196
  const int G1   = cdiv_l(N, 64);    // 782 gemm1 blocks

  // workspace layout (4-byte elems):
  //   cur[128] | off[Np] | deg[Np] | dis[Np] | scale[Np] | sd[Np]
  //   | ebuf[BW u32] | csr[BW ushort] | h8[N*32 u32] | h2[N*32 u32]
  const long Np = (N + 64) & ~63L;
  const long BW = (long)NBKT * CAP;
  int*    cur   = (int*)d_ws;
  int*    off   = cur + 128;
  int*    deg   = off + Np;
  float*  dis   = (float*)(deg + Np);
  float*  scale = dis + Np;
  float*  sd    = scale + Np;
  u32*    ebuf  = (u32*)(sd + Np);
  ushort* csr   = (ushort*)(ebuf + BW);
  u32*    h8    = (u32*)(csr + BW);      // BW ushorts = BW/2 u32 words
  u32*    h2    = h8 + (long)N * 32;

  // ---- cursors -> 0 (windows are fixed; offsets are relative) ----
  hipMemsetAsync(cur, 0, MAXB * sizeof(int), stream);

  // ---- fused: edge partition (blocks 0..NBE) || GEMM1+int8 (blocks NBE..) ----
  k_fused1<<<NBE + G1, 256, 0, stream>>>(ei, cur, ebuf, E, NBE, x, W1, h8,
                                         scale, N);

  // ---- per-bucket CSR finalize (+ sd fold) ----
  k_csr<<<NBKT, NPB, 0, stream>>>(ebuf, cur, scale, off, deg, dis, sd, csr, N);

  // ---- gather1 (int8) + relu + GEMM2 fused ----
  k_gg<<<cdiv_l(N, 16), 256, 0, stream>>>((const uint2*)h8, off, deg, csr,
                                          dis, sd, b1, W2, h2, N);

  // ---- layer-2 gather + bias ----
  k_gather2<<<cdiv_l(N, 32), 256, 0, stream>>>((const uint4*)h2, off, deg, csr,
                                               dis, b2, out, N);
}